// Round 1
// baseline (229.578 us; speedup 1.0000x reference)
//
#include <hip/hip_runtime.h>
#include <hip/hip_bf16.h>

#define DIM 768
#define HEADS 12
#define HD 64
#define SEQ 2048
#define BATCH 4
#define BHN 48          // BATCH*HEADS
#define TOK 8192        // BATCH*SEQ

#if __has_builtin(__builtin_amdgcn_exp2f)
#define EXP2F __builtin_amdgcn_exp2f
#else
#define EXP2F exp2f
#endif
// exp(s*0.125) = 2^(s * 0.125 * log2(e)); folded into Q at the QKV epilogue.
#define EXP_C 0.1803368801111244f

using short8  = __attribute__((ext_vector_type(8))) short;
using short4v = __attribute__((ext_vector_type(4))) short;
using float4v = __attribute__((ext_vector_type(4))) float;

__device__ __forceinline__ short f2b(float f) {
    union { float f; unsigned u; } v; v.f = f;
    unsigned r = v.u + 0x7FFF + ((v.u >> 16) & 1);
    return (short)(r >> 16);
}
__device__ __forceinline__ float b2f(short s) {
    union { unsigned u; float f; } v;
    v.u = ((unsigned)(unsigned short)s) << 16;
    return v.f;
}
// pack two floats to bf16x2 (round-half-up)
__device__ __forceinline__ unsigned pk2(float a, float b) {
    union { float f; unsigned u; } x, y; x.f = a; y.f = b;
    return ((x.u + 0x8000u) >> 16) | ((y.u + 0x8000u) & 0xFFFF0000u);
}

// async global->LDS copy, 16B per lane; LDS dest = uniform base + lane*16
// NOTE: one instruction covers 64 lanes x 16 B = 1024 B = 512 shorts.
typedef const __attribute__((address_space(1))) unsigned GU;
typedef __attribute__((address_space(3))) unsigned LU;
__device__ __forceinline__ void gload_lds16(const short* g, short* l) {
    __builtin_amdgcn_global_load_lds((GU*)g, (LU*)l, 16, 0, 0);
}

// ---------------- fp32 -> bf16 cast, all three tensors in one launch ----------------
__global__ void cast_all(const float* __restrict__ x, const float* __restrict__ wq,
                         const float* __restrict__ wp,
                         short* __restrict__ xb, short* __restrict__ wqb,
                         short* __restrict__ wpb, int nx4, int nq4) {
    int i = blockIdx.x * 256 + threadIdx.x;
    const float* in; short* out; int j = i;
    if (i < nx4)            { in = x;  out = xb;  }
    else if (i < nx4 + nq4) { in = wq; out = wqb; j = i - nx4; }
    else                    { in = wp; out = wpb; j = i - nx4 - nq4; }
    float4 f = ((const float4*)in)[j];
    short4 o;
    o.x = f2b(f.x); o.y = f2b(f.y); o.z = f2b(f.z); o.w = f2b(f.w);
    ((short4*)out)[j] = o;
}

// ---------------- V column-sum: Vsum[bh*64+d] = sum_n V[bh][d][n] ----------------
__global__ void vsum_kernel(const short* __restrict__ Vw, float* __restrict__ Vsum) {
    int wid  = blockIdx.x * 4 + (threadIdx.x >> 6);   // one wave per row, 3072 rows
    int lane = threadIdx.x & 63;
    const short* row = Vw + (size_t)wid * SEQ;
    float s = 0.f;
    for (int i = lane; i < SEQ; i += 64) s += b2f(row[i]);
    #pragma unroll
    for (int m = 1; m < 64; m <<= 1) s += __shfl_xor(s, m, 64);
    if (lane == 0) Vsum[wid] = s;
}

// ---------------- QKV GEMM, 128x128 tile, BK=64 (two 32-col subtiles) ----------------
// 1D grid 1152, XCD-swizzled: ybl=(gid&7)*8+(w&7), xbl=w>>3 (w=gid>>3).
// xbl 0..11: rows=x tokens, cols=Wqk -> Q (pre-scaled EXP_C) / K.
// xbl 12..17: rows=Wv, cols=x tokens -> V^T directly (32B segments).
__global__ __launch_bounds__(256, 4)
void gemm_qkv(const short* __restrict__ A, const short* __restrict__ Bw,
              short* __restrict__ Qw, short* __restrict__ Kw, short* __restrict__ Vw)
{
    __shared__ __align__(16) short As[2][128 * 32];   // 16 KB
    __shared__ __align__(16) short Bs[2][128 * 32];   // 16 KB -> 32 KB total

    const int tid  = threadIdx.x;
    const int lane = tid & 63;
    const int wave = tid >> 6;
    const int wm = (wave >> 1) * 64, wn = (wave & 1) * 64;
    const int l15 = lane & 15, quad = lane >> 4;

    // XCD-locality swizzle: 8 consecutive-y blocks per XCD reuse tiles in L2
    const int gid = blockIdx.x;
    const int w   = gid >> 3;
    const int ybl = (gid & 7) * 8 + (w & 7);   // 0..63 token block
    const int xbl = w >> 3;                    // 0..17 col block

    const bool vpart = (xbl >= 12);
    const short* rowsP = vpart ? (Bw + 1536 * 768) : A;   // Wv rows | x tokens
    const short* colsP = vpart ? A : Bw;                  // x tokens | W rows
    const int m0 = vpart ? (xbl - 12) * 128 : ybl * 128;
    const int n0 = vpart ? ybl * 128 : xbl * 128;
    const int K = DIM;

    float4v acc[4][4];
    #pragma unroll
    for (int i = 0; i < 4; i++)
        #pragma unroll
        for (int j = 0; j < 4; j++)
            acc[i][j] = (float4v){0.f, 0.f, 0.f, 0.f};

    // staging map per 128x32 subtile: 512 granules of 16B; wave stages [wave*128, +128)
    const int G0 = wave * 128 + lane;
    const int G1 = G0 + 64;
    const int rA0 = G0 >> 2, cA0 = (G0 & 3) * 8;
    const int rA1 = G1 >> 2, cA1 = (G1 & 3) * 8;
    const int ldsoff = wave * 1024;   // shorts; each instr covers 512 shorts

    for (int kt = 0; kt < K; kt += 64) {
        #pragma unroll
        for (int s = 0; s < 2; s++) {
            const int kc = kt + s * 32;
            gload_lds16(&rowsP[(size_t)(m0 + rA0) * K + kc + cA0], &As[s][ldsoff]);
            gload_lds16(&rowsP[(size_t)(m0 + rA1) * K + kc + cA1], &As[s][ldsoff + 512]);
            gload_lds16(&colsP[(size_t)(n0 + rA0) * K + kc + cA0], &Bs[s][ldsoff]);
            gload_lds16(&colsP[(size_t)(n0 + rA1) * K + kc + cA1], &Bs[s][ldsoff + 512]);
        }
        __syncthreads();   // single vmcnt drain per 64-K chunk
        #pragma unroll
        for (int s = 0; s < 2; s++) {
            short8 af[4], bfr[4];
            #pragma unroll
            for (int t = 0; t < 4; t++) {
                af[t]  = *(const short8*)&As[s][(wm + t * 16 + l15) * 32 + quad * 8];
                bfr[t] = *(const short8*)&Bs[s][(wn + t * 16 + l15) * 32 + quad * 8];
            }
            #pragma unroll
            for (int tm = 0; tm < 4; tm++)
                #pragma unroll
                for (int tn = 0; tn < 4; tn++)
                    acc[tm][tn] = __builtin_amdgcn_mfma_f32_16x16x32_bf16(af[tm], bfr[tn], acc[tm][tn], 0, 0, 0);
        }
        __syncthreads();
    }

    #pragma unroll
    for (int tm = 0; tm < 4; tm++)
        #pragma unroll
        for (int tn = 0; tn < 4; tn++)
            #pragma unroll
            for (int r = 0; r < 4; r++) {
                int row = m0 + wm + tm * 16 + quad * 4 + r;
                int col = n0 + wn + tn * 16 + l15;
                float v = acc[tm][tn][r];
                if (vpart) {
                    int hh = row >> 6, d = row & 63;
                    int b = col >> 11, n = col & 2047;
                    Vw[((size_t)(b * HEADS + hh) * 64 + d) * SEQ + n] = f2b(v);
                } else {
                    int hh = (col & 767) >> 6, d = col & 63;
                    int b = row >> 11, n = row & 2047;
                    int bh = b * HEADS + hh;
                    if (col < 768) Qw[((size_t)bh * SEQ + n) * 64 + d] = f2b(v * EXP_C);
                    else           Kw[((size_t)bh * SEQ + n) * 64 + d] = f2b(v);
                }
            }
}

// ---------------- proj GEMM, 128x64 tile, BK=64, grid 768 (fully resident) ----------------
__global__ __launch_bounds__(256, 4)
void gemm_proj(const short* __restrict__ A, const short* __restrict__ Bw,
               const float* __restrict__ bias, float* __restrict__ Out)
{
    __shared__ __align__(16) short As[2][128 * 32];   // 16 KB
    __shared__ __align__(16) short Bs[2][64 * 32];    //  8 KB -> 24 KB total

    const int tid  = threadIdx.x;
    const int lane = tid & 63;
    const int wave = tid >> 6;
    const int wm = (wave >> 1) * 64, wn = (wave & 1) * 32;
    const int l15 = lane & 15, quad = lane >> 4;

    const int gid = blockIdx.x;             // 0..767
    const int w   = gid >> 3;               // 0..95
    const int ybl = (gid & 7) * 8 + (w & 7);   // 0..63 token block
    const int xbl = w >> 3;                    // 0..11 col block
    const int m0 = ybl * 128, n0 = xbl * 64;
    const int K = DIM;

    float4v acc[4][2];
    #pragma unroll
    for (int i = 0; i < 4; i++)
        #pragma unroll
        for (int j = 0; j < 2; j++)
            acc[i][j] = (float4v){0.f, 0.f, 0.f, 0.f};

    // A subtile 128x32: 512 granules, wave stages 128 (2 instrs of 512 shorts);
    // B subtile 64x32: 256 granules, wave stages 64 (1 instr of 512 shorts)
    const int GA0 = wave * 128 + lane, GA1 = GA0 + 64;
    const int rA0 = GA0 >> 2, cA0 = (GA0 & 3) * 8;
    const int rA1 = GA1 >> 2, cA1 = (GA1 & 3) * 8;
    const int GB0 = wave * 64 + lane;
    const int rB0 = GB0 >> 2, cB0 = (GB0 & 3) * 8;
    const int ldsoffA = wave * 1024, ldsoffB = wave * 512;

    for (int kt = 0; kt < K; kt += 64) {
        #pragma unroll
        for (int s = 0; s < 2; s++) {
            const int kc = kt + s * 32;
            gload_lds16(&A [(size_t)(m0 + rA0) * K + kc + cA0], &As[s][ldsoffA]);
            gload_lds16(&A [(size_t)(m0 + rA1) * K + kc + cA1], &As[s][ldsoffA + 512]);
            gload_lds16(&Bw[(size_t)(n0 + rB0) * K + kc + cB0], &Bs[s][ldsoffB]);
        }
        __syncthreads();
        #pragma unroll
        for (int s = 0; s < 2; s++) {
            short8 af[4], bfr[2];
            #pragma unroll
            for (int t = 0; t < 4; t++)
                af[t] = *(const short8*)&As[s][(wm + t * 16 + l15) * 32 + quad * 8];
            #pragma unroll
            for (int t = 0; t < 2; t++)
                bfr[t] = *(const short8*)&Bs[s][(wn + t * 16 + l15) * 32 + quad * 8];
            #pragma unroll
            for (int tm = 0; tm < 4; tm++)
                #pragma unroll
                for (int tn = 0; tn < 2; tn++)
                    acc[tm][tn] = __builtin_amdgcn_mfma_f32_16x16x32_bf16(af[tm], bfr[tn], acc[tm][tn], 0, 0, 0);
        }
        __syncthreads();
    }

    #pragma unroll
    for (int tm = 0; tm < 4; tm++)
        #pragma unroll
        for (int tn = 0; tn < 2; tn++)
            #pragma unroll
            for (int r = 0; r < 4; r++) {
                int row = m0 + wm + tm * 16 + quad * 4 + r;
                int col = n0 + wn + tn * 16 + l15;
                Out[(size_t)row * 768 + col] = acc[tm][tn][r] + bias[col];
            }
}

// ---------------- fused double-softmax attention ----------------
// Round-10 restructure: E never round-trips through LDS. The QK^T output
// fragment (lane: q-row=l15, k=quad*4+r per 16-chunk) IS the A-fragment
// layout of v_mfma_f32_16x16x16_bf16 (k=quad*4..+3), so exp+pack feeds PV
// directly. Eb buffer eliminated -> LDS 53248->35840 B -> 4 blocks/CU.
__global__ __launch_bounds__(256, 4)
void attn_kernel(const short* __restrict__ Qw, const short* __restrict__ Kw,
                 const short* __restrict__ Vw, const float* __restrict__ Vsum,
                 short* __restrict__ Ow)
{
    __shared__ __align__(16) short KE[128 * 72];   // K tile (stride 72); init: Q stage; epi: float scratch
    __shared__ __align__(16) short Vt[64 * 136];   // V^T tile (stride 136); epi: L scratch

    const int tid  = threadIdx.x;
    const int lane = tid & 63, wave = tid >> 6;
    const int l15 = lane & 15, quad = lane >> 4;
    const int bh = blockIdx.x >> 5;
    const int n0 = (blockIdx.x & 31) * 64;
    const int wq = (wave & 2) * 16;    // wave's q-row base (0 or 32)
    const int wk = (wave & 1) * 64;    // wave's k-col half (0 or 64)

    const short* Qp = Qw + (size_t)bh * SEQ * 64;
    const short* Kp = Kw + (size_t)bh * SEQ * 64;
    const short* Vp = Vw + (size_t)bh * 64 * SEQ;

    // ones B-fragment for 16x16x16: col 0 only (l15==0), k=quad*4..+3 all 1.0
    short4v ones4;
    #pragma unroll
    for (int j = 0; j < 4; j++) ones4[j] = (l15 == 0) ? (short)0x3F80 : (short)0;

    // stage Q (64 rows x 64 cols) into KE (stride 72), read fragments, then free
    #pragma unroll
    for (int h = 0; h < 2; h++) {
        int c = tid + h * 256;
        int row = c >> 3, cc = (c & 7) * 8;
        *(short8*)&KE[row * 72 + cc] = *(const short8*)&Qp[(size_t)(n0 + row) * 64 + cc];
    }
    __syncthreads();
    short8 aq[2][2];
    #pragma unroll
    for (int nb = 0; nb < 2; nb++)
        #pragma unroll
        for (int kk = 0; kk < 2; kk++)
            aq[nb][kk] = *(const short8*)&KE[(wq + nb * 16 + l15) * 72 + kk * 32 + quad * 8];

    float4v Aacc[2][4], Lacc[2];
    #pragma unroll
    for (int mb = 0; mb < 2; mb++) {
        Lacc[mb] = (float4v){0.f, 0.f, 0.f, 0.f};
        #pragma unroll
        for (int t = 0; t < 4; t++) Aacc[mb][t] = (float4v){0.f, 0.f, 0.f, 0.f};
    }

    short8 kr[4], vr[4];
    #pragma unroll
    for (int h = 0; h < 4; h++) {
        int c = tid + h * 256;
        int row = c >> 3, cc = (c & 7) * 8;
        kr[h] = *(const short8*)&Kp[(size_t)row * 64 + cc];
        int vrow = c >> 4, vc = (c & 15) * 8;
        vr[h] = *(const short8*)&Vp[(size_t)vrow * SEQ + vc];
    }

    for (int kt = 0; kt < 16; kt++) {
        __syncthreads();   // (A) all waves done reading previous tile
        #pragma unroll
        for (int h = 0; h < 4; h++) {
            int c = tid + h * 256;
            int row = c >> 3, cc = (c & 7) * 8;
            *(short8*)&KE[row * 72 + cc] = kr[h];
            int vrow = c >> 4, vc = (c & 15) * 8;
            *(short8*)&Vt[vrow * 136 + vc] = vr[h];
        }
        __syncthreads();   // (B)

        if (kt < 15) {     // issue next-tile prefetch early; lands in regs (T14)
            #pragma unroll
            for (int h = 0; h < 4; h++) {
                int c = tid + h * 256;
                int row = c >> 3, cc = (c & 7) * 8;
                kr[h] = *(const short8*)&Kp[(size_t)((kt + 1) * 128 + row) * 64 + cc];
                int vrow = c >> 4, vc = (c & 15) * 8;
                vr[h] = *(const short8*)&Vp[(size_t)vrow * SEQ + (kt + 1) * 128 + vc];
            }
        }

        // QK^T (x32) + exp + pack into x16 A-fragments, tile by tile.
        // ae16[nb][tn]: lane (l15,quad) holds E[q=wq+nb*16+l15][wk+tn*16+quad*4 .. +3]
        short4v ae16[2][4];
        #pragma unroll
        for (int tn = 0; tn < 4; tn++) {
            const int rowK = (wk + tn * 16 + l15) * 72;
            short8 b0 = *(const short8*)&KE[rowK + quad * 8];
            short8 b1 = *(const short8*)&KE[rowK + 32 + quad * 8];
            #pragma unroll
            for (int nb = 0; nb < 2; nb++) {
                float4v s = (float4v){0.f, 0.f, 0.f, 0.f};
                s = __builtin_amdgcn_mfma_f32_16x16x32_bf16(b0, aq[nb][0], s, 0, 0, 0);
                s = __builtin_amdgcn_mfma_f32_16x16x32_bf16(b1, aq[nb][1], s, 0, 0, 0);
                float e0 = EXP2F(s[0]);
                float e1 = EXP2F(s[1]);
                float e2 = EXP2F(s[2]);
                float e3 = EXP2F(s[3]);
                union { short4v s4; uint2 u; } pe;
                pe.u.x = pk2(e0, e1);
                pe.u.y = pk2(e2, e3);
                ae16[nb][tn] = pe.s4;
            }
        }

        // PV + row-sum, all via 16x16x16 (K=16 chunks tk=0..3 over wave's 64-k half)
        #pragma unroll
        for (int tk = 0; tk < 4; tk++) {
            Lacc[0] = __builtin_amdgcn_mfma_f32_16x16x16bf16_1k(ae16[0][tk], ones4, Lacc[0], 0, 0, 0);
            Lacc[1] = __builtin_amdgcn_mfma_f32_16x16x16bf16_1k(ae16[1][tk], ones4, Lacc[1], 0, 0, 0);
            #pragma unroll
            for (int tn = 0; tn < 4; tn++) {
                short4v bv = *(const short4v*)&Vt[(tn * 16 + l15) * 136 + wk + tk * 16 + quad * 4];
                Aacc[0][tn] = __builtin_amdgcn_mfma_f32_16x16x16bf16_1k(ae16[0][tk], bv, Aacc[0][tn], 0, 0, 0);
                Aacc[1][tn] = __builtin_amdgcn_mfma_f32_16x16x16bf16_1k(ae16[1][tk], bv, Aacc[1][tn], 0, 0, 0);
            }
        }
    }

    __syncthreads();
    float* KEf = (float*)KE;
    float* Vtf = (float*)Vt;
    const int p = wave >> 1;
    if (wave & 1) {
        #pragma unroll
        for (int mb = 0; mb < 2; mb++) {
            #pragma unroll
            for (int tn = 0; tn < 4; tn++)
                #pragma unroll
                for (int r = 0; r < 4; r++)
                    KEf[(mb * 16 + tn * 4 + r) * 128 + p * 64 + lane] = Aacc[mb][tn][r];
            #pragma unroll
            for (int r = 0; r < 4; r++)
                Vtf[(mb * 4 + r) * 128 + p * 64 + lane] = Lacc[mb][r];
        }
    }
    __syncthreads();
    if (!(wave & 1)) {
        float il[2][4];
        #pragma unroll
        for (int mb = 0; mb < 2; mb++)
            #pragma unroll
            for (int r = 0; r < 4; r++) {
                float ls = Lacc[mb][r] + Vtf[(mb * 4 + r) * 128 + p * 64 + lane];
                il[mb][r] = 1.f / __shfl(ls, lane & 48, 64);
            }
        const int b = bh / HEADS, hh = bh - (bh / HEADS) * HEADS;
        #pragma unroll
        for (int tn = 0; tn < 4; tn++) {
            int d = tn * 16 + l15;
            float vs = Vsum[bh * 64 + d];
            #pragma unroll
            for (int mb = 0; mb < 2; mb++)
                #pragma unroll
                for (int r = 0; r < 4; r++) {
                    float a = Aacc[mb][tn][r] + KEf[(mb * 16 + tn * 4 + r) * 128 + p * 64 + lane];
                    int row = n0 + wq + mb * 16 + quad * 4 + r;
                    float val = (vs + a * il[mb][r]) * (1.f / 2049.f);
                    int tok = b * SEQ + row;
                    Ow[(size_t)tok * 768 + hh * 64 + d] = f2b(val);
                }
        }
    }
}

extern "C" void kernel_launch(void* const* d_in, const int* in_sizes, int n_in,
                              void* d_out, int out_size, void* d_ws, size_t ws_size,
                              hipStream_t stream) {
    const float* x      = (const float*)d_in[0];
    const float* w_qkv  = (const float*)d_in[1];
    const float* w_proj = (const float*)d_in[2];
    const float* b_proj = (const float*)d_in[3];
    float* out = (float*)d_out;

    char* ws = (char*)d_ws;
    size_t off = 0;
    auto alloc = [&](size_t bytes) {
        void* p = ws + off;
        off += (bytes + 255) & ~(size_t)255;
        return p;
    };
    short* x_bf  = (short*)alloc((size_t)TOK * DIM * 2);
    short* wq_bf = (short*)alloc((size_t)3 * DIM * DIM * 2);
    short* wp_bf = (short*)alloc((size_t)DIM * DIM * 2);
    short* Qw    = (short*)alloc((size_t)BHN * SEQ * 64 * 2);
    short* Kw    = (short*)alloc((size_t)BHN * SEQ * 64 * 2);
    short* Vw    = (short*)alloc((size_t)BHN * SEQ * 64 * 2);
    short* Ow    = (short*)alloc((size_t)TOK * DIM * 2);
    float* Vsum  = (float*)alloc((size_t)BHN * 64 * 4);

    int nx4 = TOK * DIM / 4, nq4 = 3 * DIM * DIM / 4, np4 = DIM * DIM / 4;
    int tot4 = nx4 + nq4 + np4;
    cast_all<<<tot4 / 256, 256, 0, stream>>>(x, w_qkv, w_proj, x_bf, wq_bf, wp_bf, nx4, nq4);

    gemm_qkv<<<1152, 256, 0, stream>>>(x_bf, wq_bf, Qw, Kw, Vw);

    vsum_kernel<<<BHN * 64 / 4, 256, 0, stream>>>(Vw, Vsum);

    attn_kernel<<<BHN * 32, 256, 0, stream>>>(Qw, Kw, Vw, Vsum, Ow);

    gemm_proj<<<768, 256, 0, stream>>>(Ow, wp_bf, b_proj, out);
}